// Round 14
// baseline (232.750 us; speedup 1.0000x reference)
//
#include <hip/hip_runtime.h>
#include <hip/hip_bf16.h>

#define QN 4096
#define CN 4096
#define DN 1024
#define EPSV 1e-6f

#define BM 256
#define BN 256
#define BK 64
#define NTILES (DN / BK)        // 16
#define HALF 8192               // 128x64 elems = one half-tile slab (16 KB)
#define SLAB 16384              // A or B full slab per buffer (elems)
#define BUF  32768              // one buffer = A slab + B slab (elems)

#define MATSZ ((size_t)QN * DN)

using bf16x8 = __attribute__((ext_vector_type(8))) __bf16;
using f32x4  = __attribute__((ext_vector_type(4))) float;

static __device__ __forceinline__ unsigned short f2bf_rne(float x) {
  unsigned int u = __float_as_uint(x);
  unsigned int r = (u + 0x7FFFu + ((u >> 16) & 1u)) >> 16;
  return (unsigned short)r;
}
static __device__ __forceinline__ float bf2f(unsigned short h) {
  return __uint_as_float(((unsigned int)h) << 16);
}

// async global->LDS, 16B per lane; LDS dest is wave-uniform base + lane*16
static __device__ __forceinline__ void gload_lds16(const unsigned short* g, unsigned short* l) {
  __builtin_amdgcn_global_load_lds(
      (const __attribute__((address_space(1))) unsigned int*)g,
      (__attribute__((address_space(3))) unsigned int*)l, 16, 0, 0);
}

// ws16 layout: 0:t_rgb | 1:t_flow | 2:c_rgb | 3:c_flow (bf16-rounded)
// then norms (float): tn_r[QN], tn_f[QN], cn_r[CN], cn_f[CN]

// prep: block-per-row (measured-pass form).
__global__ void prep_kernel(const float* __restrict__ tgt_r, const float* __restrict__ tgt_f,
                            const float* __restrict__ ctx_r, const float* __restrict__ ctx_f,
                            unsigned short* __restrict__ ws16, float* __restrict__ norms) {
  const int row = blockIdx.x;
  const int mat = blockIdx.y;
  const int t = threadIdx.x;
  const float* src; float eps;
  switch (mat) {
    case 0:  src = tgt_r; eps = EPSV; break;
    case 1:  src = tgt_f; eps = EPSV; break;
    case 2:  src = ctx_r; eps = 0.f;  break;
    default: src = ctx_f; eps = 0.f;  break;
  }
  unsigned short* hi = ws16 + (size_t)mat * MATSZ;
  float* nrm = norms + (size_t)mat * QN;
  const size_t base = (size_t)row * DN;
  float4 v = ((const float4*)(src + base))[t];
  float a[4] = {v.x + eps, v.y + eps, v.z + eps, v.w + eps};
  float ss = 0.f;
  unsigned short hh[4];
#pragma unroll
  for (int k = 0; k < 4; ++k) {
    hh[k] = f2bf_rne(a[k]);
    float f = bf2f(hh[k]);
    ss += f * f;
  }
  ((ushort4*)(hi + base))[t] = make_ushort4(hh[0], hh[1], hh[2], hh[3]);
#pragma unroll
  for (int o = 32; o > 0; o >>= 1) ss += __shfl_down(ss, o);
  __shared__ float red[4];
  if ((t & 63) == 0) red[t >> 6] = ss;
  __syncthreads();
  if (t == 0) nrm[row] = red[0] + red[1] + red[2] + red[3];
}

// 8-phase (4 phases/K-tile, 2 K-tiles per 8) 256x256 GEMM + distance/exp
// epilogue — m201-template port (T3+T4 counted vmcnt, T5 setprio).
// Per K-tile, phases = C-quadrants (A-half x B-half) in order
// (0,0)->(0,1)->(1,1)->(1,0): B0 regs reused at ph3; ds_reads/phase = 12,4,8,0.
// All 8 waves compute the SAME quadrant each phase (wave = 64x32 of the
// 128x128 quadrant via wr2=wid>>2, wc2=wid&3) -> half-tile consumption is
// uniform and incremental: A0,B0,B1,A1 == staging order -> per-thread FIFO
// vmcnt(4) (2 loads/stage, allow 2 stages in flight) provably covers every
// read; vmcnt NEVER drains to 0 in steady state (T4). Raw s_barrier (no
// compiler vmcnt(0) drain); lgkmcnt(0)+sched_barrier(0) before MFMA (rule 18);
// setprio(1) around MFMA cluster (T5). Chunk-XOR LDS swizzle verbatim from
// the measured-0-conflict rounds: stage source chunk (lane&7)^(lane>>3);
// read chunk (lq^(lr&7)), ksub1 = ^32 elems.
template <bool ACCUM>
__global__ __launch_bounds__(512, 2)
void gemm_kernel(const unsigned short* __restrict__ A,   // [QN, DN] bf16 (+eps)
                 const unsigned short* __restrict__ B,   // [CN, DN] bf16
                 const float* __restrict__ tn,           // ||A row||^2
                 const float* __restrict__ cn,           // ||B row||^2
                 const float* __restrict__ cw_num,       // weight numerator
                 const float* __restrict__ cw_oth,       // weight other term
                 float* __restrict__ out) {
  __shared__ unsigned short S[2 * BUF];   // 128 KB: [buf][A 256x64 | B 256x64]

  const int t = threadIdx.x;
  const int lane = t & 63;
  const int wid = t >> 6;        // 0..7
  const int wr2 = wid >> 2;      // 0..1: row-half of the 128x128 quadrant
  const int wc2 = wid & 3;       // 0..3: col-quarter of the quadrant
  const int row0 = blockIdx.y * BM;
  const int col0 = blockIdx.x * BN;

  f32x4 acc[2][2][4][2];         // [A-half][B-half][m][n] — static indices only
#pragma unroll
  for (int qa = 0; qa < 2; ++qa)
#pragma unroll
    for (int qb = 0; qb < 2; ++qb)
#pragma unroll
      for (int m = 0; m < 4; ++m)
#pragma unroll
        for (int n = 0; n < 2; ++n)
          acc[qa][qb][m][n] = (f32x4){0.f, 0.f, 0.f, 0.f};

  // ---- staging lane math (measured-0-conflict scheme) ----
  const int srw = lane >> 3;
  const int sch = (lane & 7) ^ srw;
  const size_t so0 = (size_t)(wid * 8 + srw) * DN + sch * 8;        // j=0 rows
  const size_t so1 = (size_t)(64 + wid * 8 + srw) * DN + sch * 8;   // j=1 rows
  const int lo0 = (wid * 8) * 64;
  const int lo1 = (64 + wid * 8) * 64;

  const unsigned short* pA = A + (size_t)row0 * DN;
  const unsigned short* pB = B + (size_t)col0 * DN;

  // ---- fragment read offsets (elems, row stride BK=64) ----
  const int lr = lane & 15;
  const int lq = lane >> 4;
  const int sc0 = (lq ^ (lr & 7)) * 8;
  int raoff[4][2], rboff[2][2];
#pragma unroll
  for (int m = 0; m < 4; ++m) {
    const int base = (wr2 * 64 + m * 16 + lr) * BK + sc0;
    raoff[m][0] = base; raoff[m][1] = base ^ 32;
  }
#pragma unroll
  for (int n = 0; n < 2; ++n) {
    const int base = (wc2 * 32 + n * 16 + lr) * BK + sc0;
    rboff[n][0] = base; rboff[n][1] = base ^ 32;
  }

#define STAGEH(src, ldsbase, h, kk)                                           \
  do {                                                                        \
    gload_lds16((src) + (size_t)((h) * 128) * DN + (kk) + so0,                \
                (ldsbase) + (h) * HALF + lo0);                                \
    gload_lds16((src) + (size_t)((h) * 128) * DN + (kk) + so1,                \
                (ldsbase) + (h) * HALF + lo1);                                \
  } while (0)

#define SBAR() __builtin_amdgcn_sched_barrier(0)
#define BARRIER() do { SBAR(); __builtin_amdgcn_s_barrier(); SBAR(); } while (0)
#define WAITLGKM0() do { asm volatile("s_waitcnt lgkmcnt(0)" ::: "memory"); SBAR(); } while (0)
#define WAITVM4()   do { asm volatile("s_waitcnt vmcnt(4)" ::: "memory"); SBAR(); } while (0)

  // ---- prologue: stage tile 0 (order A0,B0,B1,A1), wait first 2 stages ----
  {
    unsigned short* Na = S;
    unsigned short* Nb = S + SLAB;
    STAGEH(pA, Na, 0, 0);   // A0  (loads 1-2)
    STAGEH(pB, Nb, 0, 0);   // B0  (3-4)
    STAGEH(pB, Nb, 1, 0);   // B1  (5-6)
    STAGEH(pA, Na, 1, 0);   // A1  (7-8)
    WAITVM4();              // A0,B0 landed; B1,A1 may fly
    BARRIER();
  }

  bf16x8 Af[4][2], B0f[2][2], B1f[2][2];

  for (int tt = 0; tt < NTILES; ++tt) {
    const int b = tt & 1;
    const unsigned short* Sa = S + b * BUF;
    const unsigned short* Sb = S + b * BUF + SLAB;
    unsigned short* Na = S + (b ^ 1) * BUF;
    unsigned short* Nb = S + (b ^ 1) * BUF + SLAB;
    const int kn = (tt + 1) * BK;
    const bool notlast = (tt + 1 < NTILES);

    // -------- PH0: quadrant (0,0) — reads A-half0 (8) + B-half0 (4) --------
#pragma unroll
    for (int m = 0; m < 4; ++m) {
      Af[m][0] = *(const bf16x8*)(Sa + raoff[m][0]);
      Af[m][1] = *(const bf16x8*)(Sa + raoff[m][1]);
    }
#pragma unroll
    for (int n = 0; n < 2; ++n) {
      B0f[n][0] = *(const bf16x8*)(Sb + rboff[n][0]);
      B0f[n][1] = *(const bf16x8*)(Sb + rboff[n][1]);
    }
    if (notlast) STAGEH(pA, Na, 0, kn);          // stage next-tile A0
    BARRIER();
    WAITLGKM0();
    __builtin_amdgcn_s_setprio(1);
#pragma unroll
    for (int m = 0; m < 4; ++m)
#pragma unroll
      for (int n = 0; n < 2; ++n) {
        acc[0][0][m][n] = __builtin_amdgcn_mfma_f32_16x16x32_bf16(Af[m][0], B0f[n][0], acc[0][0][m][n], 0, 0, 0);
        acc[0][0][m][n] = __builtin_amdgcn_mfma_f32_16x16x32_bf16(Af[m][1], B0f[n][1], acc[0][0][m][n], 0, 0, 0);
      }
    __builtin_amdgcn_s_setprio(0);
    WAITVM4();               // next-tile B1's stage (s2) covered for PH1... (guards T+?); see header
    BARRIER();

    // -------- PH1: quadrant (0,1) — reads B-half1 (4); A regs reused --------
#pragma unroll
    for (int n = 0; n < 2; ++n) {
      B1f[n][0] = *(const bf16x8*)(Sb + HALF + rboff[n][0]);
      B1f[n][1] = *(const bf16x8*)(Sb + HALF + rboff[n][1]);
    }
    if (notlast) STAGEH(pB, Nb, 0, kn);          // stage next-tile B0
    BARRIER();
    WAITLGKM0();
    __builtin_amdgcn_s_setprio(1);
#pragma unroll
    for (int m = 0; m < 4; ++m)
#pragma unroll
      for (int n = 0; n < 2; ++n) {
        acc[0][1][m][n] = __builtin_amdgcn_mfma_f32_16x16x32_bf16(Af[m][0], B1f[n][0], acc[0][1][m][n], 0, 0, 0);
        acc[0][1][m][n] = __builtin_amdgcn_mfma_f32_16x16x32_bf16(Af[m][1], B1f[n][1], acc[0][1][m][n], 0, 0, 0);
      }
    __builtin_amdgcn_s_setprio(0);
    WAITVM4();
    BARRIER();

    // -------- PH2: quadrant (1,1) — reads A-half1 (8); B1 regs reused --------
#pragma unroll
    for (int m = 0; m < 4; ++m) {
      Af[m][0] = *(const bf16x8*)(Sa + HALF + raoff[m][0]);
      Af[m][1] = *(const bf16x8*)(Sa + HALF + raoff[m][1]);
    }
    if (notlast) STAGEH(pB, Nb, 1, kn);          // stage next-tile B1
    BARRIER();
    WAITLGKM0();
    __builtin_amdgcn_s_setprio(1);
#pragma unroll
    for (int m = 0; m < 4; ++m)
#pragma unroll
      for (int n = 0; n < 2; ++n) {
        acc[1][1][m][n] = __builtin_amdgcn_mfma_f32_16x16x32_bf16(Af[m][0], B1f[n][0], acc[1][1][m][n], 0, 0, 0);
        acc[1][1][m][n] = __builtin_amdgcn_mfma_f32_16x16x32_bf16(Af[m][1], B1f[n][1], acc[1][1][m][n], 0, 0, 0);
      }
    __builtin_amdgcn_s_setprio(0);
    BARRIER();               // no vmcnt: PH3 reads nothing

    // -------- PH3: quadrant (1,0) — no ds_reads; B0 regs from PH0 --------
    if (notlast) STAGEH(pA, Na, 1, kn);          // stage next-tile A1
    BARRIER();
    __builtin_amdgcn_s_setprio(1);
#pragma unroll
    for (int m = 0; m < 4; ++m)
#pragma unroll
      for (int n = 0; n < 2; ++n) {
        acc[1][0][m][n] = __builtin_amdgcn_mfma_f32_16x16x32_bf16(Af[m][0], B0f[n][0], acc[1][0][m][n], 0, 0, 0);
        acc[1][0][m][n] = __builtin_amdgcn_mfma_f32_16x16x32_bf16(Af[m][1], B0f[n][1], acc[1][0][m][n], 0, 0, 0);
      }
    __builtin_amdgcn_s_setprio(0);
    WAITVM4();               // next tile's A0,B0 stages landed before its PH0
    BARRIER();
  }

  // ---- epilogue: sq = ||t||^2+||c||^2-2*dot ; e = w*exp(-sqrt(max(sq,0))) ----
  // C/D map per frag: col = lane&15 (lr), row = (lane>>4)*4 + reg (lq*4+r)
  float cnv[2][2];
  int ccv[2][2];
#pragma unroll
  for (int qb = 0; qb < 2; ++qb)
#pragma unroll
    for (int n = 0; n < 2; ++n) {
      ccv[qb][n] = col0 + qb * 128 + wc2 * 32 + n * 16 + lr;
      cnv[qb][n] = cn[ccv[qb][n]];
    }

#pragma unroll
  for (int qa = 0; qa < 2; ++qa)
#pragma unroll
    for (int m = 0; m < 4; ++m)
#pragma unroll
      for (int r = 0; r < 4; ++r) {
        const int tq = row0 + qa * 128 + wr2 * 64 + m * 16 + lq * 4 + r;
        const float tnq = tn[tq];
        const float num = cw_num[tq], oth = cw_oth[tq];
        const float wgt = num / (num + oth);
        float* orow = out + (size_t)tq * CN;
#pragma unroll
        for (int qb = 0; qb < 2; ++qb)
#pragma unroll
          for (int n = 0; n < 2; ++n) {
            const float sq = tnq + cnv[qb][n] - 2.f * acc[qa][qb][m][n][r];
            const float d = sqrtf(fmaxf(sq, 0.f));
            const float e = wgt * __expf(-d);
            if (ACCUM) orow[ccv[qb][n]] += e;
            else       orow[ccv[qb][n]] = e;
          }
      }
}

// Per-row sum + normalize, in place (measured-pass form).
__global__ void norm_kernel(float* __restrict__ out) {
  const int row = blockIdx.x;
  const int t = threadIdx.x;
  float4* p = (float4*)(out + (size_t)row * CN);
  float4 v[4];
  float s = 0.f;
#pragma unroll
  for (int i = 0; i < 4; ++i) {
    v[i] = p[t + 256 * i];
    s += v[i].x + v[i].y + v[i].z + v[i].w;
  }
#pragma unroll
  for (int o = 32; o > 0; o >>= 1) s += __shfl_down(s, o);
  __shared__ float red[4];
  if ((t & 63) == 0) red[t >> 6] = s;
  __syncthreads();
  const float inv = 1.f / (red[0] + red[1] + red[2] + red[3]);
#pragma unroll
  for (int i = 0; i < 4; ++i) {
    v[i].x *= inv; v[i].y *= inv; v[i].z *= inv; v[i].w *= inv;
    p[t + 256 * i] = v[i];
  }
}

extern "C" void kernel_launch(void* const* d_in, const int* in_sizes, int n_in,
                              void* d_out, int out_size, void* d_ws, size_t ws_size,
                              hipStream_t stream) {
  const float* ctx_r = (const float*)d_in[0];
  const float* ctx_f = (const float*)d_in[1];
  const float* tgt_r = (const float*)d_in[2];
  const float* tgt_f = (const float*)d_in[3];
  const float* c_r   = (const float*)d_in[4];
  const float* c_f   = (const float*)d_in[5];
  float* out = (float*)d_out;
  unsigned short* ws16 = (unsigned short*)d_ws;
  float* norms = (float*)(ws16 + 4 * MATSZ);

  prep_kernel<<<dim3(QN, 4), 256, 0, stream>>>(tgt_r, tgt_f, ctx_r, ctx_f, ws16, norms);
  // rgb term: out = w_r * exp(-d_rgb)
  gemm_kernel<false><<<dim3(CN / BN, QN / BM), 512, 0, stream>>>(
      ws16 + 0 * MATSZ, ws16 + 2 * MATSZ, norms, norms + 2 * QN, c_r, c_f, out);
  // flow term: out += w_f * exp(-d_flow)
  gemm_kernel<true><<<dim3(CN / BN, QN / BM), 512, 0, stream>>>(
      ws16 + 1 * MATSZ, ws16 + 3 * MATSZ, norms + QN, norms + 3 * QN, c_f, c_r, out);
  norm_kernel<<<QN, 256, 0, stream>>>(out);
}

// Round 16
// 218.664 us; speedup vs baseline: 1.0644x; 1.0644x over previous
//
#include <hip/hip_runtime.h>
#include <hip/hip_bf16.h>

#define QN 4096
#define CN 4096
#define DN 1024
#define EPSV 1e-6f

#define BM 128
#define BN 128
#define BK 64
#define TILE (BM * BK)          // 8192 bf16 elems = 16 KB per staged tile

#define MATSZ ((size_t)QN * DN)

using bf16x8 = __attribute__((ext_vector_type(8))) __bf16;
using f32x4  = __attribute__((ext_vector_type(4))) float;

static __device__ __forceinline__ unsigned short f2bf_rne(float x) {
  unsigned int u = __float_as_uint(x);
  unsigned int r = (u + 0x7FFFu + ((u >> 16) & 1u)) >> 16;
  return (unsigned short)r;
}
static __device__ __forceinline__ float bf2f(unsigned short h) {
  return __uint_as_float(((unsigned int)h) << 16);
}

// async global->LDS, 16B per lane; LDS dest is wave-uniform base + lane*16
static __device__ __forceinline__ void gload_lds16(const unsigned short* g, unsigned short* l) {
  __builtin_amdgcn_global_load_lds(
      (const __attribute__((address_space(1))) unsigned int*)g,
      (__attribute__((address_space(3))) unsigned int*)l, 16, 0, 0);
}

// ws16 layout (ushort elems): 0:t_rgb | 1:t_flow | 2:c_rgb | 3:c_flow (bf16-rounded)
// then norms (float): tn_r[QN], tn_f[QN], cn_r[CN], cn_f[CN]
// Norms are computed from the ROUNDED values so sq = ||a~||^2+||b~||^2-2 a~.b~
// is the exact squared distance of the perturbed vectors.

__global__ void prep_kernel(const float* __restrict__ tgt_r, const float* __restrict__ tgt_f,
                            const float* __restrict__ ctx_r, const float* __restrict__ ctx_f,
                            unsigned short* __restrict__ ws16, float* __restrict__ norms) {
  const int row = blockIdx.x;
  const int mat = blockIdx.y;
  const int t = threadIdx.x;
  const float* src; float eps;
  switch (mat) {
    case 0:  src = tgt_r; eps = EPSV; break;
    case 1:  src = tgt_f; eps = EPSV; break;
    case 2:  src = ctx_r; eps = 0.f;  break;
    default: src = ctx_f; eps = 0.f;  break;
  }
  unsigned short* hi = ws16 + (size_t)mat * MATSZ;
  float* nrm = norms + (size_t)mat * QN;
  const size_t base = (size_t)row * DN;
  float4 v = ((const float4*)(src + base))[t];
  float a[4] = {v.x + eps, v.y + eps, v.z + eps, v.w + eps};
  float ss = 0.f;
  unsigned short hh[4];
#pragma unroll
  for (int k = 0; k < 4; ++k) {
    hh[k] = f2bf_rne(a[k]);
    float f = bf2f(hh[k]);         // norm of the rounded value (consistency)
    ss += f * f;
  }
  ((ushort4*)(hi + base))[t] = make_ushort4(hh[0], hh[1], hh[2], hh[3]);

#pragma unroll
  for (int o = 32; o > 0; o >>= 1) ss += __shfl_down(ss, o);
  __shared__ float red[4];
  if ((t & 63) == 0) red[t >> 6] = ss;
  __syncthreads();
  if (t == 0) nrm[row] = red[0] + red[1] + red[2] + red[3];
}

// Dual (rgb+flow) single-term bf16 GEMM + distance/exp epilogue.
// Block = 128x128 tile, 4 waves 2x2, wave = 64x64 via 4x4 frags of
// mfma_f32_16x16x32_bf16. BK=64: per barrier-pair stage 4 tiles (A_r,A_f,
// B_r,B_f; 16 global_load_lds) then 64 MFMAs in 2 K-subchunks.
// LDS 16B-chunks are XOR-swizzled by (row&7) on the *source* address to
// break the all-rows-same-bank-phase of the 128 B row stride.
__global__ __launch_bounds__(256, 2)
void gemm_kernel(const unsigned short* __restrict__ ws16,
                 const float* __restrict__ norms,
                 const float* __restrict__ c_r, const float* __restrict__ c_f,
                 float* __restrict__ out) {
  __shared__ unsigned short S[4 * TILE];   // Ar | Af | Br | Bf, each 128x64, swizzled

  const int t = threadIdx.x;
  const int lane = t & 63;
  const int wid = t >> 6;
  const int wr = wid >> 1;
  const int wc = wid & 1;
  const int row0 = blockIdx.y * BM;   // target rows
  const int col0 = blockIdx.x * BN;   // context cols

  f32x4 acc[2][4][4];
#pragma unroll
  for (int m = 0; m < 2; ++m)
#pragma unroll
    for (int i = 0; i < 4; ++i)
#pragma unroll
      for (int j = 0; j < 4; ++j)
        acc[m][i][j] = (f32x4){0.f, 0.f, 0.f, 0.f};

  // staging: per call site the block covers 32 rows x 64 cols (4 KB).
  // wave w, lane l -> LDS row w*8 + (l>>3), LDS chunk (l&7) (chunk = 8 bf16).
  // source global chunk = (l&7) ^ (l>>3)   [row&7 == l>>3 since w*8, it*32 are mult of 8]
  const int srw = lane >> 3;               // 0..7
  const int sch = (lane & 7) ^ srw;        // swizzled source chunk
  const size_t src_off = (size_t)(wid * 8 + srw) * DN + sch * 8;
  const size_t aoff = (size_t)row0 * DN + src_off;
  const size_t boff = (size_t)col0 * DN + src_off;
  unsigned short* ldsW = S + wid * 8 * BK; // + it*32*BK per call, lane*16B implicit

  const unsigned short* pAr = ws16 + 0 * MATSZ + aoff;
  const unsigned short* pAf = ws16 + 1 * MATSZ + aoff;
  const unsigned short* pBr = ws16 + 2 * MATSZ + boff;
  const unsigned short* pBf = ws16 + 3 * MATSZ + boff;

  // fragment read offsets (bf16 elems, row stride BK=64), XOR-unswizzle:
  // row R = (wr|wc)*64 + i*16 + lr  ->  R&7 == lr&7 ; chunk c = lq + 4*ksub
  const int lr = lane & 15;
  const int lq = lane >> 4;
  const int sc0 = (lq ^ (lr & 7)) * 8;     // ksub=0 chunk offset (elems)
  int ra[4], rb[4];
#pragma unroll
  for (int i = 0; i < 4; ++i) {
    ra[i] = (wr * 64 + i * 16 + lr) * BK + sc0;
    rb[i] = (wc * 64 + i * 16 + lr) * BK + sc0;
  }
  // ksub=1: chunk = (lq+4)^(lr&7) = sc0/8 ^ 4  ->  offset ^ 32 elems
#define KS1(x) ((x) ^ 32)

  for (int kc = 0; kc < DN / BK; ++kc) {
    const int k = kc * BK;
    __syncthreads();   // previous chunk fully consumed
#pragma unroll
    for (int it = 0; it < 4; ++it) {
      const size_t g = (size_t)it * 32 * DN + k;
      unsigned short* l = ldsW + it * 32 * BK;
      gload_lds16(pAr + g, l + 0 * TILE);
      gload_lds16(pAf + g, l + 1 * TILE);
      gload_lds16(pBr + g, l + 2 * TILE);
      gload_lds16(pBf + g, l + 3 * TILE);
    }
    __syncthreads();   // vmcnt drained -> LDS valid

#pragma unroll
    for (int ksub = 0; ksub < 2; ++ksub) {
      bf16x8 ar[4], af[4], br[4], bf[4];
#pragma unroll
      for (int i = 0; i < 4; ++i) {
        const int oa = ksub ? KS1(ra[i]) : ra[i];
        const int ob = ksub ? KS1(rb[i]) : rb[i];
        ar[i] = *(const bf16x8*)(S + 0 * TILE + oa);
        af[i] = *(const bf16x8*)(S + 1 * TILE + oa);
        br[i] = *(const bf16x8*)(S + 2 * TILE + ob);
        bf[i] = *(const bf16x8*)(S + 3 * TILE + ob);
      }
#pragma unroll
      for (int i = 0; i < 4; ++i)
#pragma unroll
        for (int j = 0; j < 4; ++j) {
          acc[0][i][j] = __builtin_amdgcn_mfma_f32_16x16x32_bf16(ar[i], br[j], acc[0][i][j], 0, 0, 0);
          acc[1][i][j] = __builtin_amdgcn_mfma_f32_16x16x32_bf16(af[i], bf[j], acc[1][i][j], 0, 0, 0);
        }
    }
  }

  // epilogue: sq = ||t||^2 + ||c||^2 - 2*dot ; p = w_r*exp(-d_r) + w_f*exp(-d_f)
  const float* tn_r = norms;
  const float* tn_f = norms + QN;
  const float* cn_r = norms + 2 * QN;
  const float* cn_f = norms + 3 * QN;

#pragma unroll
  for (int i = 0; i < 4; ++i) {
#pragma unroll
    for (int r = 0; r < 4; ++r) {
      const int tq = row0 + wr * 64 + i * 16 + lq * 4 + r;   // C/D row = (lane>>4)*4 + reg
      const float tnr = tn_r[tq];
      const float tnf = tn_f[tq];
      const float cr = c_r[tq], cf = c_f[tq];
      const float inv = 1.f / (cr + cf);
      const float wgr = cr * inv, wgf = cf * inv;
#pragma unroll
      for (int j = 0; j < 4; ++j) {
        const int cc = col0 + wc * 64 + j * 16 + lr;          // C/D col = lane&15
        const float sr_ = tnr + cn_r[cc] - 2.f * acc[0][i][j][r];
        const float sf_ = tnf + cn_f[cc] - 2.f * acc[1][i][j][r];
        const float dr = sqrtf(fmaxf(sr_, 0.f));
        const float df = sqrtf(fmaxf(sf_, 0.f));
        const float p = wgr * __expf(-dr) + wgf * __expf(-df);
        out[(size_t)tq * CN + cc] = p;
      }
    }
  }
}

// Per-row sum + normalize, in place. Deterministic (no atomics).
__global__ void norm_kernel(float* __restrict__ out) {
  const int row = blockIdx.x;
  const int t = threadIdx.x;
  float4* p = (float4*)(out + (size_t)row * CN);
  float4 v[4];
  float s = 0.f;
#pragma unroll
  for (int i = 0; i < 4; ++i) {
    v[i] = p[t + 256 * i];
    s += v[i].x + v[i].y + v[i].z + v[i].w;
  }
#pragma unroll
  for (int o = 32; o > 0; o >>= 1) s += __shfl_down(s, o);
  __shared__ float red[4];
  if ((t & 63) == 0) red[t >> 6] = s;
  __syncthreads();
  const float inv = 1.f / (red[0] + red[1] + red[2] + red[3]);
#pragma unroll
  for (int i = 0; i < 4; ++i) {
    v[i].x *= inv; v[i].y *= inv; v[i].z *= inv; v[i].w *= inv;
    p[t + 256 * i] = v[i];
  }
}

extern "C" void kernel_launch(void* const* d_in, const int* in_sizes, int n_in,
                              void* d_out, int out_size, void* d_ws, size_t ws_size,
                              hipStream_t stream) {
  const float* ctx_r = (const float*)d_in[0];
  const float* ctx_f = (const float*)d_in[1];
  const float* tgt_r = (const float*)d_in[2];
  const float* tgt_f = (const float*)d_in[3];
  const float* c_r   = (const float*)d_in[4];
  const float* c_f   = (const float*)d_in[5];
  float* out = (float*)d_out;
  unsigned short* ws16 = (unsigned short*)d_ws;
  float* norms = (float*)(ws16 + 4 * MATSZ);

  prep_kernel<<<dim3(QN, 4), 256, 0, stream>>>(tgt_r, tgt_f, ctx_r, ctx_f, ws16, norms);
  gemm_kernel<<<dim3(CN / BN, QN / BM), 256, 0, stream>>>(ws16, norms, c_r, c_f, out);
  norm_kernel<<<QN, 256, 0, stream>>>(out);
}